// Round 4
// baseline (44418.936 us; speedup 1.0000x reference)
//
#include <hip/hip_runtime.h>

#define MSZ (1024*1024)
#define LD 1024

// ===================== small vector kernels =====================

__global__ __launch_bounds__(1024) void prep_k(const float* __restrict__ inp, const float* __restrict__ iw,
    const float* __restrict__ ib, const float* __restrict__ aw, const float* __restrict__ ab,
    float* __restrict__ xv, float* __restrict__ atte) {
  __shared__ float red[1024];
  int t = threadIdx.x;
  float x = inp[t] * iw[t] + ib[t];
  float s = x * (aw[t] + ab[0]);
  xv[t] = x;
  red[t] = s;
  __syncthreads();
  for (int o = 512; o > 0; o >>= 1) { if (t < o) red[t] = fmaxf(red[t], red[t + o]); __syncthreads(); }
  atte[t] = expf(s - red[0]);
}

__global__ void setdiag_k(float* __restrict__ P, const float* __restrict__ atte) {
  int idx = blockIdx.x * 256 + threadIdx.x;
  int r = idx >> 10, c = idx & 1023;
  P[idx] = (r == c) ? atte[r] : 0.0f;
}

__global__ __launch_bounds__(256) void sens_k(const float* __restrict__ sw, const float* __restrict__ ssig,
    const float* __restrict__ smu, const float* __restrict__ serev, const float* __restrict__ smask,
    const float* __restrict__ xv, float* __restrict__ wns, float* __restrict__ wds) {
  __shared__ float rn[256], rd[256];
  int i = blockIdx.x, t = threadIdx.x;
  float xi = xv[i];
  float n = 0.f, d = 0.f;
  for (int j = t; j < 1024; j += 256) {
    int idx = i * 1024 + j;
    float z = ssig[idx] * (xi - smu[idx]);
    float sg = 1.0f / (1.0f + expf(-z));
    float act = sw[idx] * sg * smask[idx];
    n += act * serev[idx];
    d += act;
  }
  rn[t] = n; rd[t] = d;
  __syncthreads();
  for (int o = 128; o > 0; o >>= 1) { if (t < o) { rn[t] += rn[t + o]; rd[t] += rd[t + o]; } __syncthreads(); }
  if (t == 0) { wns[i] = rn[0]; wds[i] = rd[0]; }
}

__global__ __launch_bounds__(256) void gcn_k(const float* __restrict__ adj, const float* __restrict__ hin,
    float* __restrict__ hout, const float* __restrict__ gcw, const float* __restrict__ gcb) {
  __shared__ float red[256];
  int i = blockIdx.x, t = threadIdx.x;
  float s = 0.f;
  for (int j = t; j < 1024; j += 256) s += adj[(size_t)i * 1024 + j] * hin[j];
  red[t] = s; __syncthreads();
  for (int o = 128; o > 0; o >>= 1) { if (t < o) red[t] += red[t + o]; __syncthreads(); }
  if (t == 0) hout[i] = fmaxf(gcw[0] * red[0] + gcb[0], 0.0f);
}

__global__ __launch_bounds__(256) void matvec_n_k(const float* __restrict__ M, const float* __restrict__ v,
    float* __restrict__ out) {
  __shared__ float red[256];
  int i = blockIdx.x, t = threadIdx.x;
  float s = 0.f;
  for (int j = t; j < 1024; j += 256) s += M[(size_t)i * 1024 + j] * v[j];
  red[t] = s; __syncthreads();
  for (int o = 128; o > 0; o >>= 1) { if (t < o) red[t] += red[t + o]; __syncthreads(); }
  if (t == 0) out[i] = red[0];
}

__global__ __launch_bounds__(256) void matvec_t_k(const float* __restrict__ M, const float* __restrict__ v,
    float* __restrict__ out) {
  int j = blockIdx.x * 256 + threadIdx.x;
  float s = 0.f;
  #pragma unroll 8
  for (int i = 0; i < 1024; i++) s += M[(size_t)i * 1024 + j] * v[i];
  out[j] = s;
}

__global__ void gctrl_k(const float* __restrict__ control, const float* __restrict__ u, float* __restrict__ g) {
  int t = blockIdx.x * 256 + threadIdx.x;
  g[t] = control[t] - u[t] * (1.0f / 1024.0f);
}

__global__ void copylap_k(const float4* __restrict__ src, float4* __restrict__ dst) {
  int i = blockIdx.x * 256 + threadIdx.x;
  dst[i] = src[i];
}

// ===================== batched 64x128-tile fp32 GEMM (round-2 proven version) =====================

struct GDesc { const float* A; const float* B; float* C; const float* diag; int tri; int mode; };
struct GArgs { GDesc d[3]; };

template<int TA>
__global__ __launch_bounds__(256) void gemm64x128_k(GArgs ga) {
  GDesc de = ga.d[blockIdx.z];
  int row0 = blockIdx.y * 64, col0 = blockIdx.x * 128;
  if (de.tri && row0 + 64 <= col0) return;
  __shared__ float As[32][64];
  __shared__ float Bs[32][128];
  const float* __restrict__ A = de.A;
  const float* __restrict__ B = de.B;
  int t = threadIdx.x;
  int tx = t & 15, ty = t >> 4;
  float acc[4][8] = {};
  for (int k0 = 0; k0 < 1024; k0 += 32) {
    if (TA == 1) {
      #pragma unroll
      for (int h = 0; h < 2; h++) {
        int s = h * 256 + t;
        int bk = s >> 4, am = (s & 15) * 4;
        float4 v = *(const float4*)(A + (size_t)(k0 + bk) * LD + row0 + am);
        *(float4*)(&As[bk][am]) = v;
      }
    } else {
      #pragma unroll
      for (int h = 0; h < 2; h++) {
        int s = h * 256 + t;
        int am = s >> 3, k4 = (s & 7) * 4;
        float4 v = *(const float4*)(A + (size_t)(row0 + am) * LD + k0 + k4);
        As[k4 + 0][am] = v.x; As[k4 + 1][am] = v.y; As[k4 + 2][am] = v.z; As[k4 + 3][am] = v.w;
      }
    }
    #pragma unroll
    for (int h = 0; h < 4; h++) {
      int s = h * 256 + t;
      int bk = s >> 5, bn = (s & 31) * 4;
      float4 v = *(const float4*)(B + (size_t)(k0 + bk) * LD + col0 + bn);
      *(float4*)(&Bs[bk][bn]) = v;
    }
    __syncthreads();
    #pragma unroll
    for (int k = 0; k < 32; k++) {
      float4 a4 = *(float4*)(&As[k][tx * 4]);
      float4 b0 = *(float4*)(&Bs[k][ty * 8]);
      float4 b1 = *(float4*)(&Bs[k][ty * 8 + 4]);
      float a[4] = {a4.x, a4.y, a4.z, a4.w};
      float b[8] = {b0.x, b0.y, b0.z, b0.w, b1.x, b1.y, b1.z, b1.w};
      #pragma unroll
      for (int i = 0; i < 4; i++)
        #pragma unroll
        for (int j = 0; j < 8; j++)
          acc[i][j] += a[i] * b[j];
    }
    __syncthreads();
  }
  #pragma unroll
  for (int i = 0; i < 4; i++) {
    int gm = row0 + tx * 4 + i;
    if (de.diag) {
      int dc = gm - col0 - ty * 8;
      if (dc >= 0 && dc < 8) acc[i][dc] += de.diag[gm];
    }
    float* cp = de.C + (size_t)gm * LD + col0 + ty * 8;
    if (de.mode == 0) {
      float4 o0 = {acc[i][0], acc[i][1], acc[i][2], acc[i][3]};
      float4 o1 = {acc[i][4], acc[i][5], acc[i][6], acc[i][7]};
      *(float4*)cp = o0; *(float4*)(cp + 4) = o1;
    } else {
      float4 c0 = *(float4*)cp, c1 = *(float4*)(cp + 4);
      c0.x -= acc[i][0]; c0.y -= acc[i][1]; c0.z -= acc[i][2]; c0.w -= acc[i][3];
      c1.x -= acc[i][4]; c1.y -= acc[i][5]; c1.z -= acc[i][6]; c1.w -= acc[i][7];
      *(float4*)cp = c0; *(float4*)(cp + 4) = c1;
    }
  }
}

// ===================== persistent-grid Cholesky factor + 1024-RHS solve =====================

// Device-scope sense-reversal grid barrier. bar[0]=arrival count, bar[1]=generation.
// Requires all blocks co-resident (grid=256, LDS 51KB -> 3 blocks/CU capacity).
__device__ __forceinline__ void gsync(int* bar) {
  __syncthreads();
  if (threadIdx.x == 0) {
    __threadfence();  // agent-scope release: prior global writes visible device-wide
    int gen = __hip_atomic_load(bar + 1, __ATOMIC_RELAXED, __HIP_MEMORY_SCOPE_AGENT);
    int n = __hip_atomic_fetch_add(bar, 1, __ATOMIC_ACQ_REL, __HIP_MEMORY_SCOPE_AGENT);
    if (n + 1 == (int)gridDim.x) {
      __hip_atomic_store(bar, 0, __ATOMIC_RELAXED, __HIP_MEMORY_SCOPE_AGENT);
      __hip_atomic_store(bar + 1, gen + 1, __ATOMIC_RELEASE, __HIP_MEMORY_SCOPE_AGENT);
    } else {
      while (__hip_atomic_load(bar + 1, __ATOMIC_ACQUIRE, __HIP_MEMORY_SCOPE_AGENT) == gen) {
        __builtin_amdgcn_s_sleep(1);
      }
    }
    __threadfence();  // agent-scope acquire: invalidate stale cache lines
  }
  __syncthreads();
}

__device__ __forceinline__ void potf2_lds(float (*T)[132], int l, float r[64]) {
  #pragma unroll
  for (int k = 0; k < 64; k++) r[k] = T[l][k];
  #pragma unroll
  for (int j = 0; j < 64; j++) {
    float dj = __shfl(r[j], j, 64);
    float Ljj = sqrtf(fmaxf(dj, 1e-12f));
    float inv = 1.0f / Ljj;
    if (l == j) r[j] = Ljj;
    else if (l > j) r[j] *= inv;
    #pragma unroll
    for (int k = j + 1; k < 64; k++) {
      float Lkj = __shfl(r[j], k, 64);
      r[k] -= r[j] * Lkj;
    }
  }
}

// Mm: SPD (trailing updated in place); Lb: output L (lower); S: optional 1024 RHS -> L^-1 S in place.
__global__ __launch_bounds__(256) void cfs_k(float* __restrict__ Mm, float* __restrict__ Lb,
                                             float* __restrict__ S, int* __restrict__ bar) {
  __shared__ float shA[64][68];
  __shared__ float shB[64][132];
  int t = threadIdx.x;
  int bid = blockIdx.x;
  int nb = gridDim.x;

  if (bid == 0) {  // factor diag block 0
    #pragma unroll
    for (int h = 0; h < 4; h++) {
      int q = h * 256 + t, r = q >> 4, c4 = (q & 15) * 4;
      *(float4*)(&shB[r][c4]) = *(const float4*)(Mm + (size_t)r * LD + c4);
    }
    __syncthreads();
    if (t < 64) {
      float r[64];
      potf2_lds(shB, t, r);
      #pragma unroll
      for (int k = 0; k < 64; k++) if (k <= t) Lb[(size_t)t * LD + k] = r[k];
    }
  }
  gsync(bar);

  for (int s = 0; s < 16; s++) {
    int e = s * 64, e2 = e + 64, nt = 15 - s, rb = nt * 64;
    int nPanel = (rb + 255) / 256;
    int nRhs = S ? 4 : 0;
    int njA = nPanel + nRhs;
    // ---------- phase A: panel trsm + RHS col solves ----------
    if (bid < njA) {
      #pragma unroll
      for (int h = 0; h < 4; h++) {   // L11 -> shA (lower+diag valid)
        int q = h * 256 + t, r = q >> 4, c4 = (q & 15) * 4;
        *(float4*)(&shA[r][c4]) = *(const float4*)(Lb + (size_t)(e + r) * LD + e + c4);
      }
      __syncthreads();
      if (bid < nPanel) {
        int row = e2 + bid * 256 + t;
        if (row < 1024) {
          float y[64];
          #pragma unroll
          for (int k = 0; k < 64; k++) y[k] = Mm[(size_t)row * LD + e + k];
          #pragma unroll
          for (int kk = 0; kk < 64; kk++) {
            float v = y[kk];
            #pragma unroll
            for (int m = 0; m < kk; m++) v -= shA[kk][m] * y[m];
            y[kk] = v / shA[kk][kk];
          }
          #pragma unroll
          for (int k = 0; k < 64; k++) Lb[(size_t)row * LD + e + k] = y[k];
        }
      } else {
        int col = (bid - nPanel) * 256 + t;
        float y[64];
        #pragma unroll
        for (int k = 0; k < 64; k++) y[k] = S[(size_t)(e + k) * LD + col];
        #pragma unroll
        for (int kk = 0; kk < 64; kk++) {
          float v = y[kk];
          #pragma unroll
          for (int m = 0; m < kk; m++) v -= shA[kk][m] * y[m];
          y[kk] = v / shA[kk][kk];
        }
        #pragma unroll
        for (int k = 0; k < 64; k++) S[(size_t)(e + k) * LD + col] = y[k];
      }
    }
    gsync(bar);
    // ---------- phase B: trailing updates + lookahead potf2 of next diag ----------
    if (nt > 0) {
      if (bid == 0) {
        #pragma unroll
        for (int h = 0; h < 4; h++) {   // panel tile rows e2..e2+63 -> shA
          int q = h * 256 + t, r = q >> 4, c4 = (q & 15) * 4;
          *(float4*)(&shA[r][c4]) = *(const float4*)(Lb + (size_t)(e2 + r) * LD + e + c4);
        }
        __syncthreads();
        for (int idx = t; idx < 4096; idx += 256) {
          int r = idx >> 6, c = idx & 63;
          float a = Mm[(size_t)(e2 + r) * LD + e2 + c];
          #pragma unroll
          for (int k = 0; k < 64; k++) a -= shA[r][k] * shA[c][k];
          shB[r][c] = a;
        }
        __syncthreads();
        if (t < 64) {
          float r[64];
          potf2_lds(shB, t, r);
          #pragma unroll
          for (int k = 0; k < 64; k++) if (k <= t) Lb[(size_t)(e2 + t) * LD + e2 + k] = r[k];
        }
      } else {
        int nSyrk = nt * (nt + 1) / 2 - 1;        // excludes tile (0,0) of trailing (block 0's)
        int nSupd = S ? nt * 8 : 0;
        int njB = nSyrk + nSupd;
        for (int job = bid - 1; job < njB; job += nb - 1) {
          if (job < nSyrk) {
            int q = job + 1;
            int i0 = (int)((sqrtf(8.0f * q + 1.0f) - 1.0f) * 0.5f);
            while ((i0 + 1) * (i0 + 2) / 2 <= q) i0++;
            while (i0 * (i0 + 1) / 2 > q) i0--;
            int j0 = q - i0 * (i0 + 1) / 2;
            int ra = e + 64 * (i0 + 1), rc = e + 64 * (j0 + 1);
            #pragma unroll
            for (int h = 0; h < 4; h++) {
              int qq = h * 256 + t, r = qq >> 4, c4 = (qq & 15) * 4;
              *(float4*)(&shA[r][c4]) = *(const float4*)(Lb + (size_t)(ra + r) * LD + e + c4);
              *(float4*)(&shB[r][c4]) = *(const float4*)(Lb + (size_t)(rc + r) * LD + e + c4);
            }
            __syncthreads();
            int tx = t & 15, ty = t >> 4;
            float acc[4][4] = {};
            #pragma unroll 8
            for (int k = 0; k < 64; k++) {
              float a[4], b[4];
              #pragma unroll
              for (int i = 0; i < 4; i++) a[i] = shA[tx * 4 + i][k];
              #pragma unroll
              for (int j = 0; j < 4; j++) b[j] = shB[ty * 4 + j][k];
              #pragma unroll
              for (int i = 0; i < 4; i++)
                #pragma unroll
                for (int j = 0; j < 4; j++)
                  acc[i][j] += a[i] * b[j];
            }
            #pragma unroll
            for (int i = 0; i < 4; i++) {
              float* cp = Mm + (size_t)(ra + tx * 4 + i) * LD + rc + ty * 4;
              float4 c = *(float4*)cp;
              c.x -= acc[i][0]; c.y -= acc[i][1]; c.z -= acc[i][2]; c.w -= acc[i][3];
              *(float4*)cp = c;
            }
            __syncthreads();
          } else {
            int q = job - nSyrk;
            int i0 = (q >> 3) + 1, cb = q & 7;
            int ra = e + 64 * i0, c0 = cb * 128;
            #pragma unroll
            for (int h = 0; h < 4; h++) {
              int qq = h * 256 + t, r = qq >> 4, c4 = (qq & 15) * 4;
              *(float4*)(&shA[r][c4]) = *(const float4*)(Lb + (size_t)(ra + r) * LD + e + c4);
            }
            #pragma unroll
            for (int h = 0; h < 8; h++) {
              int qq = h * 256 + t, r = qq >> 5, c4 = (qq & 31) * 4;
              *(float4*)(&shB[r][c4]) = *(const float4*)(S + (size_t)(e + r) * LD + c0 + c4);
            }
            __syncthreads();
            int tx = t & 15, ty = t >> 4;
            float acc[4][8] = {};
            #pragma unroll 8
            for (int k = 0; k < 64; k++) {
              float a[4];
              #pragma unroll
              for (int i = 0; i < 4; i++) a[i] = shA[tx * 4 + i][k];
              float4 b0 = *(float4*)(&shB[k][ty * 8]);
              float4 b1 = *(float4*)(&shB[k][ty * 8 + 4]);
              float b[8] = {b0.x, b0.y, b0.z, b0.w, b1.x, b1.y, b1.z, b1.w};
              #pragma unroll
              for (int i = 0; i < 4; i++)
                #pragma unroll
                for (int j = 0; j < 8; j++)
                  acc[i][j] += a[i] * b[j];
            }
            #pragma unroll
            for (int i = 0; i < 4; i++) {
              float* cp = S + (size_t)(ra + tx * 4 + i) * LD + c0 + ty * 8;
              float4 v0 = *(float4*)cp, v1 = *(float4*)(cp + 4);
              v0.x -= acc[i][0]; v0.y -= acc[i][1]; v0.z -= acc[i][2]; v0.w -= acc[i][3];
              v1.x -= acc[i][4]; v1.y -= acc[i][5]; v1.z -= acc[i][6]; v1.w -= acc[i][7];
              *(float4*)cp = v0; *(float4*)(cp + 4) = v1;
            }
            __syncthreads();
          }
        }
      }
    }
    gsync(bar);
  }
}

// Mirror lower triangle to upper + add diag(atte).
__global__ __launch_bounds__(256) void mirror_k(float* __restrict__ P, const float* __restrict__ atte) {
  __shared__ float tile[64][65];
  int b = blockIdx.x, t = threadIdx.x;
  int ti, tj;
  if (b < 16) { ti = b; tj = b; }
  else {
    int p = b - 16;
    ti = (int)((1.0f + sqrtf(1.0f + 8.0f * p)) * 0.5f);
    while (ti * (ti - 1) / 2 > p) ti--;
    while ((ti + 1) * ti / 2 <= p) ti++;
    tj = p - ti * (ti - 1) / 2;
  }
  #pragma unroll
  for (int h = 0; h < 4; h++) {
    int s = h * 256 + t;
    int r = s >> 4, c4 = (s & 15) * 4;
    *(float4*)(&tile[r][c4]) = *(const float4*)(P + (size_t)(ti * 64 + r) * LD + tj * 64 + c4);
  }
  __syncthreads();
  if (ti == tj) {
    #pragma unroll
    for (int h = 0; h < 4; h++) {
      int s = h * 256 + t;
      int r = s >> 4, c4 = (s & 15) * 4;
      #pragma unroll
      for (int j = 0; j < 4; j++) {
        int c = c4 + j;
        if (c > r) P[(size_t)(ti * 64 + r) * LD + tj * 64 + c] = tile[c][r];
        else if (c == r) P[(size_t)(ti * 64 + r) * LD + tj * 64 + c] = tile[r][r] + atte[ti * 64 + r];
      }
    }
  } else {
    #pragma unroll
    for (int h = 0; h < 4; h++) {
      int s = h * 256 + t;
      int r = s >> 4, c4 = (s & 15) * 4;
      float4 o = {tile[c4 + 0][r], tile[c4 + 1][r], tile[c4 + 2][r], tile[c4 + 3][r]};
      *(float4*)(P + (size_t)(tj * 64 + r) * LD + ti * 64 + c4) = o;
    }
  }
}

// ===================== single-RHS triangular solves =====================

__global__ __launch_bounds__(1024) void trsv_fwd_k(const float* __restrict__ Lg, const float* __restrict__ bin,
    float* __restrict__ wout) {
  __shared__ float zs[1024];
  __shared__ float wsb[64];
  int t = threadIdx.x;
  zs[t] = bin[t];
  __syncthreads();
  for (int s = 0; s < 16; s++) {
    int e = s * 64;
    if (t < 64) {
      float rr[64];
      #pragma unroll
      for (int k = 0; k < 64; k++) rr[k] = Lg[(size_t)(e + t) * LD + e + k];
      float acc = zs[e + t];
      #pragma unroll
      for (int k = 0; k < 64; k++) {
        float cand = acc / rr[k];
        float wk = __shfl(cand, k, 64);
        if (t == k) wsb[k] = wk;
        if (t > k) acc -= rr[k] * wk;
      }
    }
    __syncthreads();
    if (t < 64) zs[e + t] = wsb[t];
    __syncthreads();
    if (t >= e + 64) {
      float a = zs[t];
      #pragma unroll
      for (int k = 0; k < 64; k++) a -= Lg[(size_t)t * LD + e + k] * wsb[k];
      zs[t] = a;
    }
    __syncthreads();
  }
  wout[t] = zs[t];
}

__global__ __launch_bounds__(1024) void trsv_bwd_k(const float* __restrict__ Lg, const float* __restrict__ bin,
    float* __restrict__ wout) {
  __shared__ float zs[1024];
  __shared__ float wsb[64];
  int t = threadIdx.x;
  zs[t] = bin[t];
  __syncthreads();
  for (int s = 15; s >= 0; s--) {
    int e = s * 64;
    if (t < 64) {
      float rr[64];
      #pragma unroll
      for (int k = 0; k < 64; k++) rr[k] = Lg[(size_t)(e + k) * LD + e + t];
      float acc = zs[e + t];
      #pragma unroll
      for (int k = 63; k >= 0; k--) {
        float cand = acc / rr[k];
        float wk = __shfl(cand, k, 64);
        if (t == k) wsb[k] = wk;
        if (t < k) acc -= rr[k] * wk;
      }
    }
    __syncthreads();
    if (t < 64) zs[e + t] = wsb[t];
    __syncthreads();
    if (t < e) {
      float a = zs[t];
      #pragma unroll
      for (int k = 0; k < 64; k++) a -= Lg[(size_t)(e + k) * LD + t] * wsb[k];
      zs[t] = a;
    }
    __syncthreads();
  }
  wout[t] = zs[t];
}

// ===================== fused ODE unfolds =====================
__global__ __launch_bounds__(256) void ode_k(const float* __restrict__ w, const float* __restrict__ sig,
    const float* __restrict__ mu, const float* __restrict__ erev, const float* __restrict__ mask,
    const float* __restrict__ gleak, const float* __restrict__ vleak, const float* __restrict__ cm,
    const float* __restrict__ dvec, const float* __restrict__ ctrlv, const float* __restrict__ wns,
    const float* __restrict__ wds, const float* __restrict__ ow, const float* __restrict__ ob,
    const float* __restrict__ control, float* __restrict__ dout) {
  __shared__ float wm[1024], we[1024], sgs[1024], mus[1024];
  __shared__ float red[512];
  __shared__ float vsh;
  int i = blockIdx.x, t = threadIdx.x;
  for (int j = t; j < 1024; j += 256) {
    int idx = i * 1024 + j;
    float wmv = w[idx] * mask[idx];
    wm[j] = wmv;
    we[j] = wmv * erev[idx];
    sgs[j] = sig[idx];
    mus[j] = mu[idx];
  }
  float cmt = dvec[i] + cm[i] * 6.0f + ctrlv[i];
  float gl = gleak[i], vl = vleak[i];
  float numS = wns[i], denS = wds[i];
  float v = 0.0f;
  __syncthreads();
  for (int u = 0; u < 6; u++) {
    float n = 0.f, d = 0.f;
    for (int j = t; j < 1024; j += 256) {
      float sgm = 1.0f / (1.0f + expf(-sgs[j] * (v - mus[j])));
      n += we[j] * sgm;
      d += wm[j] * sgm;
    }
    red[t] = n; red[256 + t] = d;
    __syncthreads();
    for (int o = 128; o > 0; o >>= 1) {
      if (t < o) { red[t] += red[t + o]; red[256 + t] += red[256 + t + o]; }
      __syncthreads();
    }
    if (t == 0) {
      float num = red[0] + numS, den = red[256] + denS;
      vsh = (cmt * v + gl * vl + num) / (cmt + gl + den + 1e-8f);
    }
    __syncthreads();
    v = vsh;
    __syncthreads();
  }
  if (t == 0) {
    dout[i] = v * ow[i] + ob[i];
    dout[1024 + i] = v;
    dout[2048 + 1048576 + i] = ctrlv[i] + control[i];
  }
}

// ===================== host orchestration =====================

extern "C" void kernel_launch(void* const* d_in, const int* in_sizes, int n_in,
                              void* d_out, int out_size, void* d_ws, size_t ws_size,
                              hipStream_t stream) {
  const float* inputs  = (const float*)d_in[0];
  const float* adj     = (const float*)d_in[1];
  const float* lap     = (const float*)d_in[2];
  const float* control = (const float*)d_in[3];
  const float* gleak   = (const float*)d_in[4];
  const float* vleak   = (const float*)d_in[5];
  const float* cm      = (const float*)d_in[6];
  const float* sigma   = (const float*)d_in[7];
  const float* mu      = (const float*)d_in[8];
  const float* w       = (const float*)d_in[9];
  const float* erev    = (const float*)d_in[10];
  const float* ssig    = (const float*)d_in[11];
  const float* smu     = (const float*)d_in[12];
  const float* sw      = (const float*)d_in[13];
  const float* serev   = (const float*)d_in[14];
  const float* mask    = (const float*)d_in[15];
  const float* smask   = (const float*)d_in[16];
  const float* iw      = (const float*)d_in[17];
  const float* ib      = (const float*)d_in[18];
  const float* ow      = (const float*)d_in[19];
  const float* ob      = (const float*)d_in[20];
  const float* aw      = (const float*)d_in[21];
  const float* ab      = (const float*)d_in[22];
  const float* gcw     = (const float*)d_in[23];
  const float* gcb     = (const float*)d_in[24];
  float* out = (float*)d_out;
  float* ws = (float*)d_ws;

  float* P0 = ws;
  float* P1 = ws + (size_t)MSZ;
  float* PA = ws + 2 * (size_t)MSZ;   // doubles as L buffer during Cholesky
  float* PB = ws + 3 * (size_t)MSZ;
  float* Mm = ws + 4 * (size_t)MSZ;
  float* S  = ws + 5 * (size_t)MSZ;
  float* vb = ws + 6 * (size_t)MSZ;
  float* xv = vb;            float* atte = vb + 1024;
  float* wns = vb + 2048;    float* wds  = vb + 3072;
  float* dA  = vb + 4096;    float* dB   = vb + 5120;
  float* yv  = vb + 6144;    float* tv   = vb + 7168;
  float* zv  = vb + 8192;    float* wv   = vb + 9216;
  float* uv  = vb + 10240;   float* gv   = vb + 11264;
  float* ctrlv = vb + 12288;
  int*   bar = (int*)(vb + 16384);

  hipMemsetAsync(bar, 0, 2 * sizeof(int), stream);

  prep_k<<<1, 1024, 0, stream>>>(inputs, iw, ib, aw, ab, xv, atte);
  setdiag_k<<<4096, 256, 0, stream>>>(P0, atte);
  sens_k<<<1024, 256, 0, stream>>>(sw, ssig, smu, serev, smask, xv, wns, wds);
  gcn_k<<<1024, 256, 0, stream>>>(adj, xv, dA, gcw, gcb);
  gcn_k<<<1024, 256, 0, stream>>>(adj, dA, dB, gcw, gcb);
  gcn_k<<<1024, 256, 0, stream>>>(adj, dB, dA, gcw, gcb);
  gcn_k<<<1024, 256, 0, stream>>>(adj, dA, dB, gcw, gcb);

  float* P = P0; float* Pn = P1;
  for (int it = 0; it < 6; it++) {
    GArgs g1 = {{ {P, adj, PA, nullptr, 0, 0}, {P, lap, PB, nullptr, 0, 0}, {nullptr,nullptr,nullptr,nullptr,0,0} }};
    gemm64x128_k<0><<<dim3(8, 16, 2), 256, 0, stream>>>(g1);
    GArgs g2 = {{ {PB, adj, S, nullptr, 0, 0}, {PB, lap, Mm, atte, 1, 0}, {adj, PA, Pn, nullptr, 1, 0} }};
    gemm64x128_k<1><<<dim3(8, 16, 3), 256, 0, stream>>>(g2);
    cfs_k<<<256, 256, 0, stream>>>(Mm, PA, S, bar);           // L into PA; S <- X = L^-1 S
    GArgs g3 = {{ {S, S, Pn, nullptr, 1, 1}, {nullptr,nullptr,nullptr,nullptr,0,0}, {nullptr,nullptr,nullptr,nullptr,0,0} }};
    gemm64x128_k<1><<<dim3(8, 16, 1), 256, 0, stream>>>(g3);  // Pn -= X^T X (lower)
    mirror_k<<<136, 256, 0, stream>>>(Pn, atte);              // mirror + add Q
    float* tmp = P; P = Pn; Pn = tmp;
  }

  // Final: u = K x via M u = B^T P A x
  GArgs g4 = {{ {P, lap, PB, nullptr, 0, 0}, {nullptr,nullptr,nullptr,nullptr,0,0}, {nullptr,nullptr,nullptr,nullptr,0,0} }};
  gemm64x128_k<0><<<dim3(8, 16, 1), 256, 0, stream>>>(g4);
  GArgs g5 = {{ {PB, lap, Mm, atte, 1, 0}, {nullptr,nullptr,nullptr,nullptr,0,0}, {nullptr,nullptr,nullptr,nullptr,0,0} }};
  gemm64x128_k<1><<<dim3(8, 16, 1), 256, 0, stream>>>(g5);
  cfs_k<<<256, 256, 0, stream>>>(Mm, PA, nullptr, bar);       // L into PA
  matvec_n_k<<<1024, 256, 0, stream>>>(adj, xv, yv);
  matvec_n_k<<<1024, 256, 0, stream>>>(P, yv, tv);
  matvec_t_k<<<4, 256, 0, stream>>>(lap, tv, zv);
  trsv_fwd_k<<<1, 1024, 0, stream>>>(PA, zv, wv);
  trsv_bwd_k<<<1, 1024, 0, stream>>>(PA, wv, uv);
  gctrl_k<<<4, 256, 0, stream>>>(control, uv, gv);
  matvec_t_k<<<4, 256, 0, stream>>>(lap, gv, ctrlv);

  ode_k<<<1024, 256, 0, stream>>>(w, sigma, mu, erev, mask, gleak, vleak, cm, dB, ctrlv,
                                  wns, wds, ow, ob, control, out);
  copylap_k<<<1024, 256, 0, stream>>>((const float4*)lap, (float4*)(out + 2048));
}

// Round 5
// 16537.894 us; speedup vs baseline: 2.6859x; 2.6859x over previous
//
#include <hip/hip_runtime.h>

#define MSZ (1024*1024)
#define LD 1024
#define CFS_NB 128

// ===================== small vector kernels =====================

__global__ __launch_bounds__(1024) void prep_k(const float* __restrict__ inp, const float* __restrict__ iw,
    const float* __restrict__ ib, const float* __restrict__ aw, const float* __restrict__ ab,
    float* __restrict__ xv, float* __restrict__ atte) {
  __shared__ float red[1024];
  int t = threadIdx.x;
  float x = inp[t] * iw[t] + ib[t];
  float s = x * (aw[t] + ab[0]);
  xv[t] = x;
  red[t] = s;
  __syncthreads();
  for (int o = 512; o > 0; o >>= 1) { if (t < o) red[t] = fmaxf(red[t], red[t + o]); __syncthreads(); }
  atte[t] = expf(s - red[0]);
}

__global__ void setdiag_k(float* __restrict__ P, const float* __restrict__ atte) {
  int idx = blockIdx.x * 256 + threadIdx.x;
  int r = idx >> 10, c = idx & 1023;
  P[idx] = (r == c) ? atte[r] : 0.0f;
}

__global__ __launch_bounds__(256) void sens_k(const float* __restrict__ sw, const float* __restrict__ ssig,
    const float* __restrict__ smu, const float* __restrict__ serev, const float* __restrict__ smask,
    const float* __restrict__ xv, float* __restrict__ wns, float* __restrict__ wds) {
  __shared__ float rn[256], rd[256];
  int i = blockIdx.x, t = threadIdx.x;
  float xi = xv[i];
  float n = 0.f, d = 0.f;
  for (int j = t; j < 1024; j += 256) {
    int idx = i * 1024 + j;
    float z = ssig[idx] * (xi - smu[idx]);
    float sg = 1.0f / (1.0f + expf(-z));
    float act = sw[idx] * sg * smask[idx];
    n += act * serev[idx];
    d += act;
  }
  rn[t] = n; rd[t] = d;
  __syncthreads();
  for (int o = 128; o > 0; o >>= 1) { if (t < o) { rn[t] += rn[t + o]; rd[t] += rd[t + o]; } __syncthreads(); }
  if (t == 0) { wns[i] = rn[0]; wds[i] = rd[0]; }
}

__global__ __launch_bounds__(256) void gcn_k(const float* __restrict__ adj, const float* __restrict__ hin,
    float* __restrict__ hout, const float* __restrict__ gcw, const float* __restrict__ gcb) {
  __shared__ float red[256];
  int i = blockIdx.x, t = threadIdx.x;
  float s = 0.f;
  for (int j = t; j < 1024; j += 256) s += adj[(size_t)i * 1024 + j] * hin[j];
  red[t] = s; __syncthreads();
  for (int o = 128; o > 0; o >>= 1) { if (t < o) red[t] += red[t + o]; __syncthreads(); }
  if (t == 0) hout[i] = fmaxf(gcw[0] * red[0] + gcb[0], 0.0f);
}

__global__ __launch_bounds__(256) void matvec_n_k(const float* __restrict__ M, const float* __restrict__ v,
    float* __restrict__ out) {
  __shared__ float red[256];
  int i = blockIdx.x, t = threadIdx.x;
  float s = 0.f;
  for (int j = t; j < 1024; j += 256) s += M[(size_t)i * 1024 + j] * v[j];
  red[t] = s; __syncthreads();
  for (int o = 128; o > 0; o >>= 1) { if (t < o) red[t] += red[t + o]; __syncthreads(); }
  if (t == 0) out[i] = red[0];
}

__global__ __launch_bounds__(256) void matvec_t_k(const float* __restrict__ M, const float* __restrict__ v,
    float* __restrict__ out) {
  int j = blockIdx.x * 256 + threadIdx.x;
  float s = 0.f;
  #pragma unroll 8
  for (int i = 0; i < 1024; i++) s += M[(size_t)i * 1024 + j] * v[i];
  out[j] = s;
}

__global__ void gctrl_k(const float* __restrict__ control, const float* __restrict__ u, float* __restrict__ g) {
  int t = blockIdx.x * 256 + threadIdx.x;
  g[t] = control[t] - u[t] * (1.0f / 1024.0f);
}

__global__ void copylap_k(const float4* __restrict__ src, float4* __restrict__ dst) {
  int i = blockIdx.x * 256 + threadIdx.x;
  dst[i] = src[i];
}

// ===================== batched 64x128-tile fp32 GEMM (proven) =====================

struct GDesc { const float* A; const float* B; float* C; const float* diag; int tri; int mode; };
struct GArgs { GDesc d[3]; };

template<int TA>
__global__ __launch_bounds__(256) void gemm64x128_k(GArgs ga) {
  GDesc de = ga.d[blockIdx.z];
  int row0 = blockIdx.y * 64, col0 = blockIdx.x * 128;
  if (de.tri && row0 + 64 <= col0) return;
  __shared__ float As[32][64];
  __shared__ float Bs[32][128];
  const float* __restrict__ A = de.A;
  const float* __restrict__ B = de.B;
  int t = threadIdx.x;
  int tx = t & 15, ty = t >> 4;
  float acc[4][8] = {};
  for (int k0 = 0; k0 < 1024; k0 += 32) {
    if (TA == 1) {
      #pragma unroll
      for (int h = 0; h < 2; h++) {
        int s = h * 256 + t;
        int bk = s >> 4, am = (s & 15) * 4;
        float4 v = *(const float4*)(A + (size_t)(k0 + bk) * LD + row0 + am);
        *(float4*)(&As[bk][am]) = v;
      }
    } else {
      #pragma unroll
      for (int h = 0; h < 2; h++) {
        int s = h * 256 + t;
        int am = s >> 3, k4 = (s & 7) * 4;
        float4 v = *(const float4*)(A + (size_t)(row0 + am) * LD + k0 + k4);
        As[k4 + 0][am] = v.x; As[k4 + 1][am] = v.y; As[k4 + 2][am] = v.z; As[k4 + 3][am] = v.w;
      }
    }
    #pragma unroll
    for (int h = 0; h < 4; h++) {
      int s = h * 256 + t;
      int bk = s >> 5, bn = (s & 31) * 4;
      float4 v = *(const float4*)(B + (size_t)(k0 + bk) * LD + col0 + bn);
      *(float4*)(&Bs[bk][bn]) = v;
    }
    __syncthreads();
    #pragma unroll
    for (int k = 0; k < 32; k++) {
      float4 a4 = *(float4*)(&As[k][tx * 4]);
      float4 b0 = *(float4*)(&Bs[k][ty * 8]);
      float4 b1 = *(float4*)(&Bs[k][ty * 8 + 4]);
      float a[4] = {a4.x, a4.y, a4.z, a4.w};
      float b[8] = {b0.x, b0.y, b0.z, b0.w, b1.x, b1.y, b1.z, b1.w};
      #pragma unroll
      for (int i = 0; i < 4; i++)
        #pragma unroll
        for (int j = 0; j < 8; j++)
          acc[i][j] += a[i] * b[j];
    }
    __syncthreads();
  }
  #pragma unroll
  for (int i = 0; i < 4; i++) {
    int gm = row0 + tx * 4 + i;
    if (de.diag) {
      int dc = gm - col0 - ty * 8;
      if (dc >= 0 && dc < 8) acc[i][dc] += de.diag[gm];
    }
    float* cp = de.C + (size_t)gm * LD + col0 + ty * 8;
    if (de.mode == 0) {
      float4 o0 = {acc[i][0], acc[i][1], acc[i][2], acc[i][3]};
      float4 o1 = {acc[i][4], acc[i][5], acc[i][6], acc[i][7]};
      *(float4*)cp = o0; *(float4*)(cp + 4) = o1;
    } else {
      float4 c0 = *(float4*)cp, c1 = *(float4*)(cp + 4);
      c0.x -= acc[i][0]; c0.y -= acc[i][1]; c0.z -= acc[i][2]; c0.w -= acc[i][3];
      c1.x -= acc[i][4]; c1.y -= acc[i][5]; c1.z -= acc[i][6]; c1.w -= acc[i][7];
      *(float4*)cp = c0; *(float4*)(cp + 4) = c1;
    }
  }
}

// ===================== persistent-grid Cholesky factor + 1024-RHS solve =====================

// Sense-reversal grid barrier. bar[0]=count, bar[1]=generation.
// Ordering at entry (release fence) and exit (acquire fence) ONLY — the poll is a
// RELAXED agent-scope load (coherent, but no per-poll cache invalidate; the R4
// version's ACQUIRE poll invalidated L1/L2 every iteration from every block ->
// 99.7% idle + 4x overfetch).
__device__ __forceinline__ void gsync(int* bar) {
  __syncthreads();
  if (threadIdx.x == 0) {
    __threadfence();  // release: prior global writes visible device-wide
    int gen = __hip_atomic_load(bar + 1, __ATOMIC_RELAXED, __HIP_MEMORY_SCOPE_AGENT);
    int n = __hip_atomic_fetch_add(bar, 1, __ATOMIC_RELAXED, __HIP_MEMORY_SCOPE_AGENT);
    if (n + 1 == (int)gridDim.x) {
      __hip_atomic_store(bar, 0, __ATOMIC_RELAXED, __HIP_MEMORY_SCOPE_AGENT);
      __hip_atomic_store(bar + 1, gen + 1, __ATOMIC_RELAXED, __HIP_MEMORY_SCOPE_AGENT);
    } else {
      while (__hip_atomic_load(bar + 1, __ATOMIC_RELAXED, __HIP_MEMORY_SCOPE_AGENT) == gen) {
        __builtin_amdgcn_s_sleep(16);
      }
    }
    __threadfence();  // acquire: discard stale cached lines before reading others' data
  }
  __syncthreads();
}

__device__ __forceinline__ void potf2_lds(float (*T)[132], int l, float r[64]) {
  #pragma unroll
  for (int k = 0; k < 64; k++) r[k] = T[l][k];
  #pragma unroll
  for (int j = 0; j < 64; j++) {
    float dj = __shfl(r[j], j, 64);
    float Ljj = sqrtf(fmaxf(dj, 1e-12f));
    float inv = 1.0f / Ljj;
    if (l == j) r[j] = Ljj;
    else if (l > j) r[j] *= inv;
    #pragma unroll
    for (int k = j + 1; k < 64; k++) {
      float Lkj = __shfl(r[j], k, 64);
      r[k] -= r[j] * Lkj;
    }
  }
}

// Mm: SPD (trailing updated in place); Lb: output L (lower); S: optional 1024 RHS -> L^-1 S in place.
__global__ __launch_bounds__(256) void cfs_k(float* __restrict__ Mm, float* __restrict__ Lb,
                                             float* __restrict__ S, int* __restrict__ bar) {
  __shared__ float shA[64][68];
  __shared__ float shB[64][132];
  int t = threadIdx.x;
  int bid = blockIdx.x;
  int nb = gridDim.x;

  if (bid == 0) {  // factor diag block 0
    #pragma unroll
    for (int h = 0; h < 4; h++) {
      int q = h * 256 + t, r = q >> 4, c4 = (q & 15) * 4;
      *(float4*)(&shB[r][c4]) = *(const float4*)(Mm + (size_t)r * LD + c4);
    }
    __syncthreads();
    if (t < 64) {
      float r[64];
      potf2_lds(shB, t, r);
      #pragma unroll
      for (int k = 0; k < 64; k++) if (k <= t) Lb[(size_t)t * LD + k] = r[k];
    }
  }
  gsync(bar);

  for (int s = 0; s < 16; s++) {
    int e = s * 64, e2 = e + 64, nt = 15 - s, rb = nt * 64;
    int nPanel = (rb + 255) / 256;
    int nRhs = S ? 4 : 0;
    int njA = nPanel + nRhs;
    // ---------- phase A: panel trsm + RHS col solves ----------
    if (bid < njA) {
      #pragma unroll
      for (int h = 0; h < 4; h++) {   // L11 -> shA (lower+diag valid)
        int q = h * 256 + t, r = q >> 4, c4 = (q & 15) * 4;
        *(float4*)(&shA[r][c4]) = *(const float4*)(Lb + (size_t)(e + r) * LD + e + c4);
      }
      __syncthreads();
      if (bid < nPanel) {
        int row = e2 + bid * 256 + t;
        if (row < 1024) {
          float y[64];
          #pragma unroll
          for (int k = 0; k < 64; k++) y[k] = Mm[(size_t)row * LD + e + k];
          #pragma unroll
          for (int kk = 0; kk < 64; kk++) {
            float v = y[kk];
            #pragma unroll
            for (int m = 0; m < kk; m++) v -= shA[kk][m] * y[m];
            y[kk] = v / shA[kk][kk];
          }
          #pragma unroll
          for (int k = 0; k < 64; k++) Lb[(size_t)row * LD + e + k] = y[k];
        }
      } else {
        int col = (bid - nPanel) * 256 + t;
        float y[64];
        #pragma unroll
        for (int k = 0; k < 64; k++) y[k] = S[(size_t)(e + k) * LD + col];
        #pragma unroll
        for (int kk = 0; kk < 64; kk++) {
          float v = y[kk];
          #pragma unroll
          for (int m = 0; m < kk; m++) v -= shA[kk][m] * y[m];
          y[kk] = v / shA[kk][kk];
        }
        #pragma unroll
        for (int k = 0; k < 64; k++) S[(size_t)(e + k) * LD + col] = y[k];
      }
    }
    gsync(bar);
    // ---------- phase B: trailing updates + lookahead potf2 of next diag ----------
    if (nt > 0) {
      if (bid == 0) {
        #pragma unroll
        for (int h = 0; h < 4; h++) {   // panel tile rows e2..e2+63 -> shA
          int q = h * 256 + t, r = q >> 4, c4 = (q & 15) * 4;
          *(float4*)(&shA[r][c4]) = *(const float4*)(Lb + (size_t)(e2 + r) * LD + e + c4);
        }
        __syncthreads();
        for (int idx = t; idx < 4096; idx += 256) {
          int r = idx >> 6, c = idx & 63;
          float a = Mm[(size_t)(e2 + r) * LD + e2 + c];
          #pragma unroll
          for (int k = 0; k < 64; k++) a -= shA[r][k] * shA[c][k];
          shB[r][c] = a;
        }
        __syncthreads();
        if (t < 64) {
          float r[64];
          potf2_lds(shB, t, r);
          #pragma unroll
          for (int k = 0; k < 64; k++) if (k <= t) Lb[(size_t)(e2 + t) * LD + e2 + k] = r[k];
        }
      } else {
        int nSyrk = nt * (nt + 1) / 2 - 1;        // excludes tile (0,0) of trailing (block 0's)
        int nSupd = S ? nt * 8 : 0;
        int njB = nSyrk + nSupd;
        for (int job = bid - 1; job < njB; job += nb - 1) {
          if (job < nSyrk) {
            int q = job + 1;
            int i0 = (int)((sqrtf(8.0f * q + 1.0f) - 1.0f) * 0.5f);
            while ((i0 + 1) * (i0 + 2) / 2 <= q) i0++;
            while (i0 * (i0 + 1) / 2 > q) i0--;
            int j0 = q - i0 * (i0 + 1) / 2;
            int ra = e + 64 * (i0 + 1), rc = e + 64 * (j0 + 1);
            #pragma unroll
            for (int h = 0; h < 4; h++) {
              int qq = h * 256 + t, r = qq >> 4, c4 = (qq & 15) * 4;
              *(float4*)(&shA[r][c4]) = *(const float4*)(Lb + (size_t)(ra + r) * LD + e + c4);
              *(float4*)(&shB[r][c4]) = *(const float4*)(Lb + (size_t)(rc + r) * LD + e + c4);
            }
            __syncthreads();
            int tx = t & 15, ty = t >> 4;
            float acc[4][4] = {};
            #pragma unroll 8
            for (int k = 0; k < 64; k++) {
              float a[4], b[4];
              #pragma unroll
              for (int i = 0; i < 4; i++) a[i] = shA[tx * 4 + i][k];
              #pragma unroll
              for (int j = 0; j < 4; j++) b[j] = shB[ty * 4 + j][k];
              #pragma unroll
              for (int i = 0; i < 4; i++)
                #pragma unroll
                for (int j = 0; j < 4; j++)
                  acc[i][j] += a[i] * b[j];
            }
            #pragma unroll
            for (int i = 0; i < 4; i++) {
              float* cp = Mm + (size_t)(ra + tx * 4 + i) * LD + rc + ty * 4;
              float4 c = *(float4*)cp;
              c.x -= acc[i][0]; c.y -= acc[i][1]; c.z -= acc[i][2]; c.w -= acc[i][3];
              *(float4*)cp = c;
            }
            __syncthreads();
          } else {
            int q = job - nSyrk;
            int i0 = (q >> 3) + 1, cb = q & 7;
            int ra = e + 64 * i0, c0 = cb * 128;
            #pragma unroll
            for (int h = 0; h < 4; h++) {
              int qq = h * 256 + t, r = qq >> 4, c4 = (qq & 15) * 4;
              *(float4*)(&shA[r][c4]) = *(const float4*)(Lb + (size_t)(ra + r) * LD + e + c4);
            }
            #pragma unroll
            for (int h = 0; h < 8; h++) {
              int qq = h * 256 + t, r = qq >> 5, c4 = (qq & 31) * 4;
              *(float4*)(&shB[r][c4]) = *(const float4*)(S + (size_t)(e + r) * LD + c0 + c4);
            }
            __syncthreads();
            int tx = t & 15, ty = t >> 4;
            float acc[4][8] = {};
            #pragma unroll 8
            for (int k = 0; k < 64; k++) {
              float a[4];
              #pragma unroll
              for (int i = 0; i < 4; i++) a[i] = shA[tx * 4 + i][k];
              float4 b0 = *(float4*)(&shB[k][ty * 8]);
              float4 b1 = *(float4*)(&shB[k][ty * 8 + 4]);
              float b[8] = {b0.x, b0.y, b0.z, b0.w, b1.x, b1.y, b1.z, b1.w};
              #pragma unroll
              for (int i = 0; i < 4; i++)
                #pragma unroll
                for (int j = 0; j < 8; j++)
                  acc[i][j] += a[i] * b[j];
            }
            #pragma unroll
            for (int i = 0; i < 4; i++) {
              float* cp = S + (size_t)(ra + tx * 4 + i) * LD + c0 + ty * 8;
              float4 v0 = *(float4*)cp, v1 = *(float4*)(cp + 4);
              v0.x -= acc[i][0]; v0.y -= acc[i][1]; v0.z -= acc[i][2]; v0.w -= acc[i][3];
              v1.x -= acc[i][4]; v1.y -= acc[i][5]; v1.z -= acc[i][6]; v1.w -= acc[i][7];
              *(float4*)cp = v0; *(float4*)(cp + 4) = v1;
            }
            __syncthreads();
          }
        }
      }
    }
    gsync(bar);
  }
}

// Mirror lower triangle to upper + add diag(atte).
__global__ __launch_bounds__(256) void mirror_k(float* __restrict__ P, const float* __restrict__ atte) {
  __shared__ float tile[64][65];
  int b = blockIdx.x, t = threadIdx.x;
  int ti, tj;
  if (b < 16) { ti = b; tj = b; }
  else {
    int p = b - 16;
    ti = (int)((1.0f + sqrtf(1.0f + 8.0f * p)) * 0.5f);
    while (ti * (ti - 1) / 2 > p) ti--;
    while ((ti + 1) * ti / 2 <= p) ti++;
    tj = p - ti * (ti - 1) / 2;
  }
  #pragma unroll
  for (int h = 0; h < 4; h++) {
    int s = h * 256 + t;
    int r = s >> 4, c4 = (s & 15) * 4;
    *(float4*)(&tile[r][c4]) = *(const float4*)(P + (size_t)(ti * 64 + r) * LD + tj * 64 + c4);
  }
  __syncthreads();
  if (ti == tj) {
    #pragma unroll
    for (int h = 0; h < 4; h++) {
      int s = h * 256 + t;
      int r = s >> 4, c4 = (s & 15) * 4;
      #pragma unroll
      for (int j = 0; j < 4; j++) {
        int c = c4 + j;
        if (c > r) P[(size_t)(ti * 64 + r) * LD + tj * 64 + c] = tile[c][r];
        else if (c == r) P[(size_t)(ti * 64 + r) * LD + tj * 64 + c] = tile[r][r] + atte[ti * 64 + r];
      }
    }
  } else {
    #pragma unroll
    for (int h = 0; h < 4; h++) {
      int s = h * 256 + t;
      int r = s >> 4, c4 = (s & 15) * 4;
      float4 o = {tile[c4 + 0][r], tile[c4 + 1][r], tile[c4 + 2][r], tile[c4 + 3][r]};
      *(float4*)(P + (size_t)(tj * 64 + r) * LD + ti * 64 + c4) = o;
    }
  }
}

// ===================== single-RHS triangular solves =====================

__global__ __launch_bounds__(1024) void trsv_fwd_k(const float* __restrict__ Lg, const float* __restrict__ bin,
    float* __restrict__ wout) {
  __shared__ float zs[1024];
  __shared__ float wsb[64];
  int t = threadIdx.x;
  zs[t] = bin[t];
  __syncthreads();
  for (int s = 0; s < 16; s++) {
    int e = s * 64;
    if (t < 64) {
      float rr[64];
      #pragma unroll
      for (int k = 0; k < 64; k++) rr[k] = Lg[(size_t)(e + t) * LD + e + k];
      float acc = zs[e + t];
      #pragma unroll
      for (int k = 0; k < 64; k++) {
        float cand = acc / rr[k];
        float wk = __shfl(cand, k, 64);
        if (t == k) wsb[k] = wk;
        if (t > k) acc -= rr[k] * wk;
      }
    }
    __syncthreads();
    if (t < 64) zs[e + t] = wsb[t];
    __syncthreads();
    if (t >= e + 64) {
      float a = zs[t];
      #pragma unroll
      for (int k = 0; k < 64; k++) a -= Lg[(size_t)t * LD + e + k] * wsb[k];
      zs[t] = a;
    }
    __syncthreads();
  }
  wout[t] = zs[t];
}

__global__ __launch_bounds__(1024) void trsv_bwd_k(const float* __restrict__ Lg, const float* __restrict__ bin,
    float* __restrict__ wout) {
  __shared__ float zs[1024];
  __shared__ float wsb[64];
  int t = threadIdx.x;
  zs[t] = bin[t];
  __syncthreads();
  for (int s = 15; s >= 0; s--) {
    int e = s * 64;
    if (t < 64) {
      float rr[64];
      #pragma unroll
      for (int k = 0; k < 64; k++) rr[k] = Lg[(size_t)(e + k) * LD + e + t];
      float acc = zs[e + t];
      #pragma unroll
      for (int k = 63; k >= 0; k--) {
        float cand = acc / rr[k];
        float wk = __shfl(cand, k, 64);
        if (t == k) wsb[k] = wk;
        if (t < k) acc -= rr[k] * wk;
      }
    }
    __syncthreads();
    if (t < 64) zs[e + t] = wsb[t];
    __syncthreads();
    if (t < e) {
      float a = zs[t];
      #pragma unroll
      for (int k = 0; k < 64; k++) a -= Lg[(size_t)(e + k) * LD + t] * wsb[k];
      zs[t] = a;
    }
    __syncthreads();
  }
  wout[t] = zs[t];
}

// ===================== fused ODE unfolds =====================
__global__ __launch_bounds__(256) void ode_k(const float* __restrict__ w, const float* __restrict__ sig,
    const float* __restrict__ mu, const float* __restrict__ erev, const float* __restrict__ mask,
    const float* __restrict__ gleak, const float* __restrict__ vleak, const float* __restrict__ cm,
    const float* __restrict__ dvec, const float* __restrict__ ctrlv, const float* __restrict__ wns,
    const float* __restrict__ wds, const float* __restrict__ ow, const float* __restrict__ ob,
    const float* __restrict__ control, float* __restrict__ dout) {
  __shared__ float wm[1024], we[1024], sgs[1024], mus[1024];
  __shared__ float red[512];
  __shared__ float vsh;
  int i = blockIdx.x, t = threadIdx.x;
  for (int j = t; j < 1024; j += 256) {
    int idx = i * 1024 + j;
    float wmv = w[idx] * mask[idx];
    wm[j] = wmv;
    we[j] = wmv * erev[idx];
    sgs[j] = sig[idx];
    mus[j] = mu[idx];
  }
  float cmt = dvec[i] + cm[i] * 6.0f + ctrlv[i];
  float gl = gleak[i], vl = vleak[i];
  float numS = wns[i], denS = wds[i];
  float v = 0.0f;
  __syncthreads();
  for (int u = 0; u < 6; u++) {
    float n = 0.f, d = 0.f;
    for (int j = t; j < 1024; j += 256) {
      float sgm = 1.0f / (1.0f + expf(-sgs[j] * (v - mus[j])));
      n += we[j] * sgm;
      d += wm[j] * sgm;
    }
    red[t] = n; red[256 + t] = d;
    __syncthreads();
    for (int o = 128; o > 0; o >>= 1) {
      if (t < o) { red[t] += red[t + o]; red[256 + t] += red[256 + t + o]; }
      __syncthreads();
    }
    if (t == 0) {
      float num = red[0] + numS, den = red[256] + denS;
      vsh = (cmt * v + gl * vl + num) / (cmt + gl + den + 1e-8f);
    }
    __syncthreads();
    v = vsh;
    __syncthreads();
  }
  if (t == 0) {
    dout[i] = v * ow[i] + ob[i];
    dout[1024 + i] = v;
    dout[2048 + 1048576 + i] = ctrlv[i] + control[i];
  }
}

// ===================== host orchestration =====================

extern "C" void kernel_launch(void* const* d_in, const int* in_sizes, int n_in,
                              void* d_out, int out_size, void* d_ws, size_t ws_size,
                              hipStream_t stream) {
  const float* inputs  = (const float*)d_in[0];
  const float* adj     = (const float*)d_in[1];
  const float* lap     = (const float*)d_in[2];
  const float* control = (const float*)d_in[3];
  const float* gleak   = (const float*)d_in[4];
  const float* vleak   = (const float*)d_in[5];
  const float* cm      = (const float*)d_in[6];
  const float* sigma   = (const float*)d_in[7];
  const float* mu      = (const float*)d_in[8];
  const float* w       = (const float*)d_in[9];
  const float* erev    = (const float*)d_in[10];
  const float* ssig    = (const float*)d_in[11];
  const float* smu     = (const float*)d_in[12];
  const float* sw      = (const float*)d_in[13];
  const float* serev   = (const float*)d_in[14];
  const float* mask    = (const float*)d_in[15];
  const float* smask   = (const float*)d_in[16];
  const float* iw      = (const float*)d_in[17];
  const float* ib      = (const float*)d_in[18];
  const float* ow      = (const float*)d_in[19];
  const float* ob      = (const float*)d_in[20];
  const float* aw      = (const float*)d_in[21];
  const float* ab      = (const float*)d_in[22];
  const float* gcw     = (const float*)d_in[23];
  const float* gcb     = (const float*)d_in[24];
  float* out = (float*)d_out;
  float* ws = (float*)d_ws;

  float* P0 = ws;
  float* P1 = ws + (size_t)MSZ;
  float* PA = ws + 2 * (size_t)MSZ;   // doubles as L buffer during Cholesky
  float* PB = ws + 3 * (size_t)MSZ;
  float* Mm = ws + 4 * (size_t)MSZ;
  float* S  = ws + 5 * (size_t)MSZ;
  float* vb = ws + 6 * (size_t)MSZ;
  float* xv = vb;            float* atte = vb + 1024;
  float* wns = vb + 2048;    float* wds  = vb + 3072;
  float* dA  = vb + 4096;    float* dB   = vb + 5120;
  float* yv  = vb + 6144;    float* tv   = vb + 7168;
  float* zv  = vb + 8192;    float* wv   = vb + 9216;
  float* uv  = vb + 10240;   float* gv   = vb + 11264;
  float* ctrlv = vb + 12288;
  int*   bar = (int*)(vb + 16384);

  hipMemsetAsync(bar, 0, 2 * sizeof(int), stream);

  prep_k<<<1, 1024, 0, stream>>>(inputs, iw, ib, aw, ab, xv, atte);
  setdiag_k<<<4096, 256, 0, stream>>>(P0, atte);
  sens_k<<<1024, 256, 0, stream>>>(sw, ssig, smu, serev, smask, xv, wns, wds);
  gcn_k<<<1024, 256, 0, stream>>>(adj, xv, dA, gcw, gcb);
  gcn_k<<<1024, 256, 0, stream>>>(adj, dA, dB, gcw, gcb);
  gcn_k<<<1024, 256, 0, stream>>>(adj, dB, dA, gcw, gcb);
  gcn_k<<<1024, 256, 0, stream>>>(adj, dA, dB, gcw, gcb);

  float* P = P0; float* Pn = P1;
  for (int it = 0; it < 6; it++) {
    GArgs g1 = {{ {P, adj, PA, nullptr, 0, 0}, {P, lap, PB, nullptr, 0, 0}, {nullptr,nullptr,nullptr,nullptr,0,0} }};
    gemm64x128_k<0><<<dim3(8, 16, 2), 256, 0, stream>>>(g1);
    GArgs g2 = {{ {PB, adj, S, nullptr, 0, 0}, {PB, lap, Mm, atte, 1, 0}, {adj, PA, Pn, nullptr, 1, 0} }};
    gemm64x128_k<1><<<dim3(8, 16, 3), 256, 0, stream>>>(g2);
    cfs_k<<<CFS_NB, 256, 0, stream>>>(Mm, PA, S, bar);        // L into PA; S <- X = L^-1 S
    GArgs g3 = {{ {S, S, Pn, nullptr, 1, 1}, {nullptr,nullptr,nullptr,nullptr,0,0}, {nullptr,nullptr,nullptr,nullptr,0,0} }};
    gemm64x128_k<1><<<dim3(8, 16, 1), 256, 0, stream>>>(g3);  // Pn -= X^T X (lower)
    mirror_k<<<136, 256, 0, stream>>>(Pn, atte);              // mirror + add Q
    float* tmp = P; P = Pn; Pn = tmp;
  }

  // Final: u = K x via M u = B^T P A x
  GArgs g4 = {{ {P, lap, PB, nullptr, 0, 0}, {nullptr,nullptr,nullptr,nullptr,0,0}, {nullptr,nullptr,nullptr,nullptr,0,0} }};
  gemm64x128_k<0><<<dim3(8, 16, 1), 256, 0, stream>>>(g4);
  GArgs g5 = {{ {PB, lap, Mm, atte, 1, 0}, {nullptr,nullptr,nullptr,nullptr,0,0}, {nullptr,nullptr,nullptr,nullptr,0,0} }};
  gemm64x128_k<1><<<dim3(8, 16, 1), 256, 0, stream>>>(g5);
  cfs_k<<<CFS_NB, 256, 0, stream>>>(Mm, PA, nullptr, bar);    // L into PA
  matvec_n_k<<<1024, 256, 0, stream>>>(adj, xv, yv);
  matvec_n_k<<<1024, 256, 0, stream>>>(P, yv, tv);
  matvec_t_k<<<4, 256, 0, stream>>>(lap, tv, zv);
  trsv_fwd_k<<<1, 1024, 0, stream>>>(PA, zv, wv);
  trsv_bwd_k<<<1, 1024, 0, stream>>>(PA, wv, uv);
  gctrl_k<<<4, 256, 0, stream>>>(control, uv, gv);
  matvec_t_k<<<4, 256, 0, stream>>>(lap, gv, ctrlv);

  ode_k<<<1024, 256, 0, stream>>>(w, sigma, mu, erev, mask, gleak, vleak, cm, dB, ctrlv,
                                  wns, wds, ow, ob, control, out);
  copylap_k<<<1024, 256, 0, stream>>>((const float4*)lap, (float4*)(out + 2048));
}

// Round 6
// 15747.636 us; speedup vs baseline: 2.8207x; 1.0502x over previous
//
#include <hip/hip_runtime.h>

#define MSZ (1024*1024)
#define LD 1024
#define CFS_NB 128

// ===================== small vector kernels =====================

__global__ __launch_bounds__(1024) void prep_k(const float* __restrict__ inp, const float* __restrict__ iw,
    const float* __restrict__ ib, const float* __restrict__ aw, const float* __restrict__ ab,
    float* __restrict__ xv, float* __restrict__ atte) {
  __shared__ float red[1024];
  int t = threadIdx.x;
  float x = inp[t] * iw[t] + ib[t];
  float s = x * (aw[t] + ab[0]);
  xv[t] = x;
  red[t] = s;
  __syncthreads();
  for (int o = 512; o > 0; o >>= 1) { if (t < o) red[t] = fmaxf(red[t], red[t + o]); __syncthreads(); }
  atte[t] = expf(s - red[0]);
}

__global__ void setdiag_k(float* __restrict__ P, const float* __restrict__ atte) {
  int idx = blockIdx.x * 256 + threadIdx.x;
  int r = idx >> 10, c = idx & 1023;
  P[idx] = (r == c) ? atte[r] : 0.0f;
}

__global__ __launch_bounds__(256) void sens_k(const float* __restrict__ sw, const float* __restrict__ ssig,
    const float* __restrict__ smu, const float* __restrict__ serev, const float* __restrict__ smask,
    const float* __restrict__ xv, float* __restrict__ wns, float* __restrict__ wds) {
  __shared__ float rn[256], rd[256];
  int i = blockIdx.x, t = threadIdx.x;
  float xi = xv[i];
  float n = 0.f, d = 0.f;
  for (int j = t; j < 1024; j += 256) {
    int idx = i * 1024 + j;
    float z = ssig[idx] * (xi - smu[idx]);
    float sg = 1.0f / (1.0f + expf(-z));
    float act = sw[idx] * sg * smask[idx];
    n += act * serev[idx];
    d += act;
  }
  rn[t] = n; rd[t] = d;
  __syncthreads();
  for (int o = 128; o > 0; o >>= 1) { if (t < o) { rn[t] += rn[t + o]; rd[t] += rd[t + o]; } __syncthreads(); }
  if (t == 0) { wns[i] = rn[0]; wds[i] = rd[0]; }
}

__global__ __launch_bounds__(256) void gcn_k(const float* __restrict__ adj, const float* __restrict__ hin,
    float* __restrict__ hout, const float* __restrict__ gcw, const float* __restrict__ gcb) {
  __shared__ float red[256];
  int i = blockIdx.x, t = threadIdx.x;
  float s = 0.f;
  for (int j = t; j < 1024; j += 256) s += adj[(size_t)i * 1024 + j] * hin[j];
  red[t] = s; __syncthreads();
  for (int o = 128; o > 0; o >>= 1) { if (t < o) red[t] += red[t + o]; __syncthreads(); }
  if (t == 0) hout[i] = fmaxf(gcw[0] * red[0] + gcb[0], 0.0f);
}

__global__ __launch_bounds__(256) void matvec_n_k(const float* __restrict__ M, const float* __restrict__ v,
    float* __restrict__ out) {
  __shared__ float red[256];
  int i = blockIdx.x, t = threadIdx.x;
  float s = 0.f;
  for (int j = t; j < 1024; j += 256) s += M[(size_t)i * 1024 + j] * v[j];
  red[t] = s; __syncthreads();
  for (int o = 128; o > 0; o >>= 1) { if (t < o) red[t] += red[t + o]; __syncthreads(); }
  if (t == 0) out[i] = red[0];
}

__global__ __launch_bounds__(256) void matvec_t_k(const float* __restrict__ M, const float* __restrict__ v,
    float* __restrict__ out) {
  int j = blockIdx.x * 256 + threadIdx.x;
  float s = 0.f;
  #pragma unroll 8
  for (int i = 0; i < 1024; i++) s += M[(size_t)i * 1024 + j] * v[i];
  out[j] = s;
}

__global__ void gctrl_k(const float* __restrict__ control, const float* __restrict__ u, float* __restrict__ g) {
  int t = blockIdx.x * 256 + threadIdx.x;
  g[t] = control[t] - u[t] * (1.0f / 1024.0f);
}

__global__ void copylap_k(const float4* __restrict__ src, float4* __restrict__ dst) {
  int i = blockIdx.x * 256 + threadIdx.x;
  dst[i] = src[i];
}

// ===================== batched 64x128-tile fp32 GEMM (proven) =====================

struct GDesc { const float* A; const float* B; float* C; const float* diag; int tri; int mode; };
struct GArgs { GDesc d[3]; };

template<int TA>
__global__ __launch_bounds__(256) void gemm64x128_k(GArgs ga) {
  GDesc de = ga.d[blockIdx.z];
  int row0 = blockIdx.y * 64, col0 = blockIdx.x * 128;
  if (de.tri && row0 + 64 <= col0) return;
  __shared__ float As[32][64];
  __shared__ float Bs[32][128];
  const float* __restrict__ A = de.A;
  const float* __restrict__ B = de.B;
  int t = threadIdx.x;
  int tx = t & 15, ty = t >> 4;
  float acc[4][8] = {};
  for (int k0 = 0; k0 < 1024; k0 += 32) {
    if (TA == 1) {
      #pragma unroll
      for (int h = 0; h < 2; h++) {
        int s = h * 256 + t;
        int bk = s >> 4, am = (s & 15) * 4;
        float4 v = *(const float4*)(A + (size_t)(k0 + bk) * LD + row0 + am);
        *(float4*)(&As[bk][am]) = v;
      }
    } else {
      #pragma unroll
      for (int h = 0; h < 2; h++) {
        int s = h * 256 + t;
        int am = s >> 3, k4 = (s & 7) * 4;
        float4 v = *(const float4*)(A + (size_t)(row0 + am) * LD + k0 + k4);
        As[k4 + 0][am] = v.x; As[k4 + 1][am] = v.y; As[k4 + 2][am] = v.z; As[k4 + 3][am] = v.w;
      }
    }
    #pragma unroll
    for (int h = 0; h < 4; h++) {
      int s = h * 256 + t;
      int bk = s >> 5, bn = (s & 31) * 4;
      float4 v = *(const float4*)(B + (size_t)(k0 + bk) * LD + col0 + bn);
      *(float4*)(&Bs[bk][bn]) = v;
    }
    __syncthreads();
    #pragma unroll
    for (int k = 0; k < 32; k++) {
      float4 a4 = *(float4*)(&As[k][tx * 4]);
      float4 b0 = *(float4*)(&Bs[k][ty * 8]);
      float4 b1 = *(float4*)(&Bs[k][ty * 8 + 4]);
      float a[4] = {a4.x, a4.y, a4.z, a4.w};
      float b[8] = {b0.x, b0.y, b0.z, b0.w, b1.x, b1.y, b1.z, b1.w};
      #pragma unroll
      for (int i = 0; i < 4; i++)
        #pragma unroll
        for (int j = 0; j < 8; j++)
          acc[i][j] += a[i] * b[j];
    }
    __syncthreads();
  }
  #pragma unroll
  for (int i = 0; i < 4; i++) {
    int gm = row0 + tx * 4 + i;
    if (de.diag) {
      int dc = gm - col0 - ty * 8;
      if (dc >= 0 && dc < 8) acc[i][dc] += de.diag[gm];
    }
    float* cp = de.C + (size_t)gm * LD + col0 + ty * 8;
    if (de.mode == 0) {
      float4 o0 = {acc[i][0], acc[i][1], acc[i][2], acc[i][3]};
      float4 o1 = {acc[i][4], acc[i][5], acc[i][6], acc[i][7]};
      *(float4*)cp = o0; *(float4*)(cp + 4) = o1;
    } else {
      float4 c0 = *(float4*)cp, c1 = *(float4*)(cp + 4);
      c0.x -= acc[i][0]; c0.y -= acc[i][1]; c0.z -= acc[i][2]; c0.w -= acc[i][3];
      c1.x -= acc[i][4]; c1.y -= acc[i][5]; c1.z -= acc[i][6]; c1.w -= acc[i][7];
      *(float4*)cp = c0; *(float4*)(cp + 4) = c1;
    }
  }
}

// ===================== persistent-grid Cholesky factor + 1024-RHS solve =====================

// Distributed-flag master barrier (no centralized RMW — R5's fetch_add serialized
// 128 LLC round-trips ≈ 60us/barrier). Layout: bar[b*32] = arrival gen of block b
// (padded line each); bar[nb*32] = published generation. Ordering: one release
// fence before arrival store, one acquire fence after generation observed.
__device__ __forceinline__ void gsync(int* __restrict__ bar, int gen) {
  int t = threadIdx.x;
  int nb = gridDim.x;
  __syncthreads();
  if (blockIdx.x == 0) {
    if (t >= 1 && t < nb) {
      while (__hip_atomic_load(bar + t * 32, __ATOMIC_RELAXED, __HIP_MEMORY_SCOPE_AGENT) < gen)
        __builtin_amdgcn_s_sleep(2);
    }
    __syncthreads();
    if (t == 0) {
      __threadfence();  // release own writes + invalidate before reading others'
      __hip_atomic_store(bar + nb * 32, gen, __ATOMIC_RELAXED, __HIP_MEMORY_SCOPE_AGENT);
    }
    __syncthreads();
  } else {
    if (t == 0) {
      __threadfence();  // release: own prior writes visible before arrival
      __hip_atomic_store(bar + blockIdx.x * 32, gen, __ATOMIC_RELAXED, __HIP_MEMORY_SCOPE_AGENT);
      while (__hip_atomic_load(bar + nb * 32, __ATOMIC_RELAXED, __HIP_MEMORY_SCOPE_AGENT) < gen)
        __builtin_amdgcn_s_sleep(8);
      __threadfence();  // acquire: discard stale lines before reading others' data
    }
    __syncthreads();
  }
}

__device__ __forceinline__ void potf2_lds(float (*T)[132], int l, float r[64]) {
  #pragma unroll
  for (int k = 0; k < 64; k++) r[k] = T[l][k];
  #pragma unroll
  for (int j = 0; j < 64; j++) {
    float dj = __shfl(r[j], j, 64);
    float Ljj = sqrtf(fmaxf(dj, 1e-12f));
    float inv = 1.0f / Ljj;
    if (l == j) r[j] = Ljj;
    else if (l > j) r[j] *= inv;
    #pragma unroll
    for (int k = j + 1; k < 64; k++) {
      float Lkj = __shfl(r[j], k, 64);
      r[k] -= r[j] * Lkj;
    }
  }
}

// Mm: SPD (trailing updated in place); Lb: output L (lower); S: optional 1024 RHS -> L^-1 S in place.
__global__ __launch_bounds__(256) void cfs_k(float* __restrict__ Mm, float* __restrict__ Lb,
                                             float* __restrict__ S, int* __restrict__ bar) {
  __shared__ float shA[64][68];
  __shared__ float shB[64][132];
  int t = threadIdx.x;
  int bid = blockIdx.x;
  int nb = gridDim.x;
  int gen = 0;

  if (bid == 0) {  // factor diag block 0
    #pragma unroll
    for (int h = 0; h < 4; h++) {
      int q = h * 256 + t, r = q >> 4, c4 = (q & 15) * 4;
      *(float4*)(&shB[r][c4]) = *(const float4*)(Mm + (size_t)r * LD + c4);
    }
    __syncthreads();
    if (t < 64) {
      float r[64];
      potf2_lds(shB, t, r);
      #pragma unroll
      for (int k = 0; k < 64; k++) if (k <= t) Lb[(size_t)t * LD + k] = r[k];
    }
  }
  gsync(bar, ++gen);

  for (int s = 0; s < 16; s++) {
    int e = s * 64, e2 = e + 64, nt = 15 - s, rb = nt * 64;
    int nPanel = (rb + 255) / 256;
    int nRhs = S ? 4 : 0;
    int njA = nPanel + nRhs;
    // ---------- phase A: panel trsm + RHS col solves ----------
    if (bid < njA) {
      #pragma unroll
      for (int h = 0; h < 4; h++) {   // L11 -> shA (lower+diag valid)
        int q = h * 256 + t, r = q >> 4, c4 = (q & 15) * 4;
        *(float4*)(&shA[r][c4]) = *(const float4*)(Lb + (size_t)(e + r) * LD + e + c4);
      }
      __syncthreads();
      if (bid < nPanel) {
        int row = e2 + bid * 256 + t;
        if (row < 1024) {
          float y[64];
          #pragma unroll
          for (int k = 0; k < 64; k++) y[k] = Mm[(size_t)row * LD + e + k];
          #pragma unroll
          for (int kk = 0; kk < 64; kk++) {
            float v = y[kk];
            #pragma unroll
            for (int m = 0; m < kk; m++) v -= shA[kk][m] * y[m];
            y[kk] = v / shA[kk][kk];
          }
          #pragma unroll
          for (int k = 0; k < 64; k++) Lb[(size_t)row * LD + e + k] = y[k];
        }
      } else {
        int col = (bid - nPanel) * 256 + t;
        float y[64];
        #pragma unroll
        for (int k = 0; k < 64; k++) y[k] = S[(size_t)(e + k) * LD + col];
        #pragma unroll
        for (int kk = 0; kk < 64; kk++) {
          float v = y[kk];
          #pragma unroll
          for (int m = 0; m < kk; m++) v -= shA[kk][m] * y[m];
          y[kk] = v / shA[kk][kk];
        }
        #pragma unroll
        for (int k = 0; k < 64; k++) S[(size_t)(e + k) * LD + col] = y[k];
      }
    }
    gsync(bar, ++gen);
    // ---------- phase B: trailing updates + lookahead potf2 of next diag ----------
    if (nt > 0) {
      if (bid == 0) {
        #pragma unroll
        for (int h = 0; h < 4; h++) {   // panel rows e2..e2+63 -> shA ; Mm diag tile -> shB
          int q = h * 256 + t, r = q >> 4, c4 = (q & 15) * 4;
          *(float4*)(&shA[r][c4]) = *(const float4*)(Lb + (size_t)(e2 + r) * LD + e + c4);
          *(float4*)(&shB[r][c4]) = *(const float4*)(Mm + (size_t)(e2 + r) * LD + e2 + c4);
        }
        __syncthreads();
        {
          int tx = t & 15, ty = t >> 4;
          float acc[4][4] = {};
          #pragma unroll 8
          for (int k = 0; k < 64; k++) {
            float a[4], b[4];
            #pragma unroll
            for (int i = 0; i < 4; i++) a[i] = shA[tx * 4 + i][k];
            #pragma unroll
            for (int j = 0; j < 4; j++) b[j] = shA[ty * 4 + j][k];
            #pragma unroll
            for (int i = 0; i < 4; i++)
              #pragma unroll
              for (int j = 0; j < 4; j++)
                acc[i][j] += a[i] * b[j];
          }
          #pragma unroll
          for (int i = 0; i < 4; i++)
            #pragma unroll
            for (int j = 0; j < 4; j++)
              shB[tx * 4 + i][ty * 4 + j] -= acc[i][j];
        }
        __syncthreads();
        if (t < 64) {
          float r[64];
          potf2_lds(shB, t, r);
          #pragma unroll
          for (int k = 0; k < 64; k++) if (k <= t) Lb[(size_t)(e2 + t) * LD + e2 + k] = r[k];
        }
      } else {
        int nSyrk = nt * (nt + 1) / 2 - 1;        // excludes trailing tile (0,0) (block 0's)
        int nSupd = S ? nt * 8 : 0;
        int njB = nSyrk + nSupd;
        for (int job = bid - 1; job < njB; job += nb - 1) {
          if (job < nSyrk) {
            int q = job + 1;
            int i0 = (int)((sqrtf(8.0f * q + 1.0f) - 1.0f) * 0.5f);
            while ((i0 + 1) * (i0 + 2) / 2 <= q) i0++;
            while (i0 * (i0 + 1) / 2 > q) i0--;
            int j0 = q - i0 * (i0 + 1) / 2;
            int ra = e + 64 * (i0 + 1), rc = e + 64 * (j0 + 1);
            #pragma unroll
            for (int h = 0; h < 4; h++) {
              int qq = h * 256 + t, r = qq >> 4, c4 = (qq & 15) * 4;
              *(float4*)(&shA[r][c4]) = *(const float4*)(Lb + (size_t)(ra + r) * LD + e + c4);
              *(float4*)(&shB[r][c4]) = *(const float4*)(Lb + (size_t)(rc + r) * LD + e + c4);
            }
            __syncthreads();
            int tx = t & 15, ty = t >> 4;
            float acc[4][4] = {};
            #pragma unroll 8
            for (int k = 0; k < 64; k++) {
              float a[4], b[4];
              #pragma unroll
              for (int i = 0; i < 4; i++) a[i] = shA[tx * 4 + i][k];
              #pragma unroll
              for (int j = 0; j < 4; j++) b[j] = shB[ty * 4 + j][k];
              #pragma unroll
              for (int i = 0; i < 4; i++)
                #pragma unroll
                for (int j = 0; j < 4; j++)
                  acc[i][j] += a[i] * b[j];
            }
            #pragma unroll
            for (int i = 0; i < 4; i++) {
              float* cp = Mm + (size_t)(ra + tx * 4 + i) * LD + rc + ty * 4;
              float4 c = *(float4*)cp;
              c.x -= acc[i][0]; c.y -= acc[i][1]; c.z -= acc[i][2]; c.w -= acc[i][3];
              *(float4*)cp = c;
            }
            __syncthreads();
          } else {
            int q = job - nSyrk;
            int i0 = (q >> 3) + 1, cb = q & 7;
            int ra = e + 64 * i0, c0 = cb * 128;
            #pragma unroll
            for (int h = 0; h < 4; h++) {
              int qq = h * 256 + t, r = qq >> 4, c4 = (qq & 15) * 4;
              *(float4*)(&shA[r][c4]) = *(const float4*)(Lb + (size_t)(ra + r) * LD + e + c4);
            }
            #pragma unroll
            for (int h = 0; h < 8; h++) {
              int qq = h * 256 + t, r = qq >> 5, c4 = (qq & 31) * 4;
              *(float4*)(&shB[r][c4]) = *(const float4*)(S + (size_t)(e + r) * LD + c0 + c4);
            }
            __syncthreads();
            int tx = t & 15, ty = t >> 4;
            float acc[4][8] = {};
            #pragma unroll 8
            for (int k = 0; k < 64; k++) {
              float a[4];
              #pragma unroll
              for (int i = 0; i < 4; i++) a[i] = shA[tx * 4 + i][k];
              float4 b0 = *(float4*)(&shB[k][ty * 8]);
              float4 b1 = *(float4*)(&shB[k][ty * 8 + 4]);
              float b[8] = {b0.x, b0.y, b0.z, b0.w, b1.x, b1.y, b1.z, b1.w};
              #pragma unroll
              for (int i = 0; i < 4; i++)
                #pragma unroll
                for (int j = 0; j < 8; j++)
                  acc[i][j] += a[i] * b[j];
            }
            #pragma unroll
            for (int i = 0; i < 4; i++) {
              float* cp = S + (size_t)(ra + tx * 4 + i) * LD + c0 + ty * 8;
              float4 v0 = *(float4*)cp, v1 = *(float4*)(cp + 4);
              v0.x -= acc[i][0]; v0.y -= acc[i][1]; v0.z -= acc[i][2]; v0.w -= acc[i][3];
              v1.x -= acc[i][4]; v1.y -= acc[i][5]; v1.z -= acc[i][6]; v1.w -= acc[i][7];
              *(float4*)cp = v0; *(float4*)(cp + 4) = v1;
            }
            __syncthreads();
          }
        }
      }
    }
    gsync(bar, ++gen);
  }
}

// Mirror lower triangle to upper + add diag(atte).
__global__ __launch_bounds__(256) void mirror_k(float* __restrict__ P, const float* __restrict__ atte) {
  __shared__ float tile[64][65];
  int b = blockIdx.x, t = threadIdx.x;
  int ti, tj;
  if (b < 16) { ti = b; tj = b; }
  else {
    int p = b - 16;
    ti = (int)((1.0f + sqrtf(1.0f + 8.0f * p)) * 0.5f);
    while (ti * (ti - 1) / 2 > p) ti--;
    while ((ti + 1) * ti / 2 <= p) ti++;
    tj = p - ti * (ti - 1) / 2;
  }
  #pragma unroll
  for (int h = 0; h < 4; h++) {
    int s = h * 256 + t;
    int r = s >> 4, c4 = (s & 15) * 4;
    *(float4*)(&tile[r][c4]) = *(const float4*)(P + (size_t)(ti * 64 + r) * LD + tj * 64 + c4);
  }
  __syncthreads();
  if (ti == tj) {
    #pragma unroll
    for (int h = 0; h < 4; h++) {
      int s = h * 256 + t;
      int r = s >> 4, c4 = (s & 15) * 4;
      #pragma unroll
      for (int j = 0; j < 4; j++) {
        int c = c4 + j;
        if (c > r) P[(size_t)(ti * 64 + r) * LD + tj * 64 + c] = tile[c][r];
        else if (c == r) P[(size_t)(ti * 64 + r) * LD + tj * 64 + c] = tile[r][r] + atte[ti * 64 + r];
      }
    }
  } else {
    #pragma unroll
    for (int h = 0; h < 4; h++) {
      int s = h * 256 + t;
      int r = s >> 4, c4 = (s & 15) * 4;
      float4 o = {tile[c4 + 0][r], tile[c4 + 1][r], tile[c4 + 2][r], tile[c4 + 3][r]};
      *(float4*)(P + (size_t)(tj * 64 + r) * LD + ti * 64 + c4) = o;
    }
  }
}

// ===================== single-RHS triangular solves =====================

__global__ __launch_bounds__(1024) void trsv_fwd_k(const float* __restrict__ Lg, const float* __restrict__ bin,
    float* __restrict__ wout) {
  __shared__ float zs[1024];
  __shared__ float wsb[64];
  int t = threadIdx.x;
  zs[t] = bin[t];
  __syncthreads();
  for (int s = 0; s < 16; s++) {
    int e = s * 64;
    if (t < 64) {
      float rr[64];
      #pragma unroll
      for (int k = 0; k < 64; k++) rr[k] = Lg[(size_t)(e + t) * LD + e + k];
      float acc = zs[e + t];
      #pragma unroll
      for (int k = 0; k < 64; k++) {
        float cand = acc / rr[k];
        float wk = __shfl(cand, k, 64);
        if (t == k) wsb[k] = wk;
        if (t > k) acc -= rr[k] * wk;
      }
    }
    __syncthreads();
    if (t < 64) zs[e + t] = wsb[t];
    __syncthreads();
    if (t >= e + 64) {
      float a = zs[t];
      #pragma unroll
      for (int k = 0; k < 64; k++) a -= Lg[(size_t)t * LD + e + k] * wsb[k];
      zs[t] = a;
    }
    __syncthreads();
  }
  wout[t] = zs[t];
}

__global__ __launch_bounds__(1024) void trsv_bwd_k(const float* __restrict__ Lg, const float* __restrict__ bin,
    float* __restrict__ wout) {
  __shared__ float zs[1024];
  __shared__ float wsb[64];
  int t = threadIdx.x;
  zs[t] = bin[t];
  __syncthreads();
  for (int s = 15; s >= 0; s--) {
    int e = s * 64;
    if (t < 64) {
      float rr[64];
      #pragma unroll
      for (int k = 0; k < 64; k++) rr[k] = Lg[(size_t)(e + k) * LD + e + t];
      float acc = zs[e + t];
      #pragma unroll
      for (int k = 63; k >= 0; k--) {
        float cand = acc / rr[k];
        float wk = __shfl(cand, k, 64);
        if (t == k) wsb[k] = wk;
        if (t < k) acc -= rr[k] * wk;
      }
    }
    __syncthreads();
    if (t < 64) zs[e + t] = wsb[t];
    __syncthreads();
    if (t < e) {
      float a = zs[t];
      #pragma unroll
      for (int k = 0; k < 64; k++) a -= Lg[(size_t)(e + k) * LD + t] * wsb[k];
      zs[t] = a;
    }
    __syncthreads();
  }
  wout[t] = zs[t];
}

// ===================== fused ODE unfolds =====================
__global__ __launch_bounds__(256) void ode_k(const float* __restrict__ w, const float* __restrict__ sig,
    const float* __restrict__ mu, const float* __restrict__ erev, const float* __restrict__ mask,
    const float* __restrict__ gleak, const float* __restrict__ vleak, const float* __restrict__ cm,
    const float* __restrict__ dvec, const float* __restrict__ ctrlv, const float* __restrict__ wns,
    const float* __restrict__ wds, const float* __restrict__ ow, const float* __restrict__ ob,
    const float* __restrict__ control, float* __restrict__ dout) {
  __shared__ float wm[1024], we[1024], sgs[1024], mus[1024];
  __shared__ float red[512];
  __shared__ float vsh;
  int i = blockIdx.x, t = threadIdx.x;
  for (int j = t; j < 1024; j += 256) {
    int idx = i * 1024 + j;
    float wmv = w[idx] * mask[idx];
    wm[j] = wmv;
    we[j] = wmv * erev[idx];
    sgs[j] = sig[idx];
    mus[j] = mu[idx];
  }
  float cmt = dvec[i] + cm[i] * 6.0f + ctrlv[i];
  float gl = gleak[i], vl = vleak[i];
  float numS = wns[i], denS = wds[i];
  float v = 0.0f;
  __syncthreads();
  for (int u = 0; u < 6; u++) {
    float n = 0.f, d = 0.f;
    for (int j = t; j < 1024; j += 256) {
      float sgm = 1.0f / (1.0f + expf(-sgs[j] * (v - mus[j])));
      n += we[j] * sgm;
      d += wm[j] * sgm;
    }
    red[t] = n; red[256 + t] = d;
    __syncthreads();
    for (int o = 128; o > 0; o >>= 1) {
      if (t < o) { red[t] += red[t + o]; red[256 + t] += red[256 + t + o]; }
      __syncthreads();
    }
    if (t == 0) {
      float num = red[0] + numS, den = red[256] + denS;
      vsh = (cmt * v + gl * vl + num) / (cmt + gl + den + 1e-8f);
    }
    __syncthreads();
    v = vsh;
    __syncthreads();
  }
  if (t == 0) {
    dout[i] = v * ow[i] + ob[i];
    dout[1024 + i] = v;
    dout[2048 + 1048576 + i] = ctrlv[i] + control[i];
  }
}

// ===================== host orchestration =====================

extern "C" void kernel_launch(void* const* d_in, const int* in_sizes, int n_in,
                              void* d_out, int out_size, void* d_ws, size_t ws_size,
                              hipStream_t stream) {
  const float* inputs  = (const float*)d_in[0];
  const float* adj     = (const float*)d_in[1];
  const float* lap     = (const float*)d_in[2];
  const float* control = (const float*)d_in[3];
  const float* gleak   = (const float*)d_in[4];
  const float* vleak   = (const float*)d_in[5];
  const float* cm      = (const float*)d_in[6];
  const float* sigma   = (const float*)d_in[7];
  const float* mu      = (const float*)d_in[8];
  const float* w       = (const float*)d_in[9];
  const float* erev    = (const float*)d_in[10];
  const float* ssig    = (const float*)d_in[11];
  const float* smu     = (const float*)d_in[12];
  const float* sw      = (const float*)d_in[13];
  const float* serev   = (const float*)d_in[14];
  const float* mask    = (const float*)d_in[15];
  const float* smask   = (const float*)d_in[16];
  const float* iw      = (const float*)d_in[17];
  const float* ib      = (const float*)d_in[18];
  const float* ow      = (const float*)d_in[19];
  const float* ob      = (const float*)d_in[20];
  const float* aw      = (const float*)d_in[21];
  const float* ab      = (const float*)d_in[22];
  const float* gcw     = (const float*)d_in[23];
  const float* gcb     = (const float*)d_in[24];
  float* out = (float*)d_out;
  float* ws = (float*)d_ws;

  float* P0 = ws;
  float* P1 = ws + (size_t)MSZ;
  float* PA = ws + 2 * (size_t)MSZ;   // doubles as L buffer during Cholesky
  float* PB = ws + 3 * (size_t)MSZ;
  float* Mm = ws + 4 * (size_t)MSZ;
  float* S  = ws + 5 * (size_t)MSZ;
  float* vb = ws + 6 * (size_t)MSZ;
  float* xv = vb;            float* atte = vb + 1024;
  float* wns = vb + 2048;    float* wds  = vb + 3072;
  float* dA  = vb + 4096;    float* dB   = vb + 5120;
  float* yv  = vb + 6144;    float* tv   = vb + 7168;
  float* zv  = vb + 8192;    float* wv   = vb + 9216;
  float* uv  = vb + 10240;   float* gv   = vb + 11264;
  float* ctrlv = vb + 12288;
  int*   bar = (int*)(vb + 16384);   // (CFS_NB+1) padded lines of 32 ints

  const size_t barBytes = (size_t)(CFS_NB + 1) * 32 * sizeof(int);

  prep_k<<<1, 1024, 0, stream>>>(inputs, iw, ib, aw, ab, xv, atte);
  setdiag_k<<<4096, 256, 0, stream>>>(P0, atte);
  sens_k<<<1024, 256, 0, stream>>>(sw, ssig, smu, serev, smask, xv, wns, wds);
  gcn_k<<<1024, 256, 0, stream>>>(adj, xv, dA, gcw, gcb);
  gcn_k<<<1024, 256, 0, stream>>>(adj, dA, dB, gcw, gcb);
  gcn_k<<<1024, 256, 0, stream>>>(adj, dB, dA, gcw, gcb);
  gcn_k<<<1024, 256, 0, stream>>>(adj, dA, dB, gcw, gcb);

  float* P = P0; float* Pn = P1;
  for (int it = 0; it < 6; it++) {
    GArgs g1 = {{ {P, adj, PA, nullptr, 0, 0}, {P, lap, PB, nullptr, 0, 0}, {nullptr,nullptr,nullptr,nullptr,0,0} }};
    gemm64x128_k<0><<<dim3(8, 16, 2), 256, 0, stream>>>(g1);
    GArgs g2 = {{ {PB, adj, S, nullptr, 0, 0}, {PB, lap, Mm, atte, 1, 0}, {adj, PA, Pn, nullptr, 1, 0} }};
    gemm64x128_k<1><<<dim3(8, 16, 3), 256, 0, stream>>>(g2);
    hipMemsetAsync(bar, 0, barBytes, stream);
    cfs_k<<<CFS_NB, 256, 0, stream>>>(Mm, PA, S, bar);        // L into PA; S <- X = L^-1 S
    GArgs g3 = {{ {S, S, Pn, nullptr, 1, 1}, {nullptr,nullptr,nullptr,nullptr,0,0}, {nullptr,nullptr,nullptr,nullptr,0,0} }};
    gemm64x128_k<1><<<dim3(8, 16, 1), 256, 0, stream>>>(g3);  // Pn -= X^T X (lower)
    mirror_k<<<136, 256, 0, stream>>>(Pn, atte);              // mirror + add Q
    float* tmp = P; P = Pn; Pn = tmp;
  }

  // Final: u = K x via M u = B^T P A x
  GArgs g4 = {{ {P, lap, PB, nullptr, 0, 0}, {nullptr,nullptr,nullptr,nullptr,0,0}, {nullptr,nullptr,nullptr,nullptr,0,0} }};
  gemm64x128_k<0><<<dim3(8, 16, 1), 256, 0, stream>>>(g4);
  GArgs g5 = {{ {PB, lap, Mm, atte, 1, 0}, {nullptr,nullptr,nullptr,nullptr,0,0}, {nullptr,nullptr,nullptr,nullptr,0,0} }};
  gemm64x128_k<1><<<dim3(8, 16, 1), 256, 0, stream>>>(g5);
  hipMemsetAsync(bar, 0, barBytes, stream);
  cfs_k<<<CFS_NB, 256, 0, stream>>>(Mm, PA, nullptr, bar);    // L into PA
  matvec_n_k<<<1024, 256, 0, stream>>>(adj, xv, yv);
  matvec_n_k<<<1024, 256, 0, stream>>>(P, yv, tv);
  matvec_t_k<<<4, 256, 0, stream>>>(lap, tv, zv);
  trsv_fwd_k<<<1, 1024, 0, stream>>>(PA, zv, wv);
  trsv_bwd_k<<<1, 1024, 0, stream>>>(PA, wv, uv);
  gctrl_k<<<4, 256, 0, stream>>>(control, uv, gv);
  matvec_t_k<<<4, 256, 0, stream>>>(lap, gv, ctrlv);

  ode_k<<<1024, 256, 0, stream>>>(w, sigma, mu, erev, mask, gleak, vleak, cm, dB, ctrlv,
                                  wns, wds, ow, ob, control, out);
  copylap_k<<<1024, 256, 0, stream>>>((const float4*)lap, (float4*)(out + 2048));
}